// Round 1
// baseline (1491.514 us; speedup 1.0000x reference)
//
#include <hip/hip_runtime.h>
#include <cstdint>
#include <cstddef>

#define ROWS  2048
#define DIM   1024
#define VOCAB 50257
#define CUT0  2000
#define CUT1  10000

// ---------------------------------------------------------------------------
// Generic tiled fp32 GEMM: C[M,N] = A[M,K] @ B[K,N] (+ bias), row-major.
// BM=BN=128, BK=16, 256 threads, 8x8 acc per thread.
// Columns >= special_col are redirected to aux[row*2 + (col-special_col)]
// (used only by the root GEMM to capture the 2 cluster logits).
// ---------------------------------------------------------------------------
__global__ __launch_bounds__(256)
void gemm_f32(const float* __restrict__ A, const float* __restrict__ B,
              const float* __restrict__ bias, float* __restrict__ C,
              float* __restrict__ aux, int M, int N, int K, int ldc,
              int special_col)
{
    __shared__ float As[16][128];
    __shared__ float Bs[16][128];

    const int t  = threadIdx.x;
    const int tx = t & 15;          // 0..15  -> 8 cols each
    const int ty = t >> 4;          // 0..15  -> 8 rows each
    const int row0 = blockIdx.y * 128;
    const int col0 = blockIdx.x * 128;

    float acc[8][8];
#pragma unroll
    for (int i = 0; i < 8; ++i)
#pragma unroll
        for (int j = 0; j < 8; ++j) acc[i][j] = 0.f;

    const int am = t >> 1;          // 0..127 : A row within tile
    const int ak = (t & 1) * 8;     // 0 or 8 : k offset within tile

    for (int k0 = 0; k0 < K; k0 += 16) {
        // --- load A tile (128 x 16), float4 x2 per thread ---
        const float* ap = A + (size_t)(row0 + am) * K + k0 + ak;
        float4 a0 = *(const float4*)(ap);
        float4 a1 = *(const float4*)(ap + 4);
        As[ak + 0][am] = a0.x; As[ak + 1][am] = a0.y;
        As[ak + 2][am] = a0.z; As[ak + 3][am] = a0.w;
        As[ak + 4][am] = a1.x; As[ak + 5][am] = a1.y;
        As[ak + 6][am] = a1.z; As[ak + 7][am] = a1.w;

        // --- load B tile (16 x 128), 8 scalar loads per thread (N may be odd) ---
        {
            const int bk = t >> 4;          // 0..15
            const int bn = (t & 15) * 8;    // 0..120
            const float* bp = B + (size_t)(k0 + bk) * N;
#pragma unroll
            for (int j = 0; j < 8; ++j) {
                int c = col0 + bn + j;
                Bs[bk][bn + j] = (c < N) ? bp[c] : 0.f;
            }
        }
        __syncthreads();

#pragma unroll
        for (int kk = 0; kk < 16; ++kk) {
            float a[8], b[8];
#pragma unroll
            for (int i = 0; i < 8; ++i) a[i] = As[kk][ty * 8 + i];
#pragma unroll
            for (int j = 0; j < 8; ++j) b[j] = Bs[kk][tx * 8 + j];
#pragma unroll
            for (int i = 0; i < 8; ++i)
#pragma unroll
                for (int j = 0; j < 8; ++j)
                    acc[i][j] = fmaf(a[i], b[j], acc[i][j]);
        }
        __syncthreads();
    }

    // --- epilogue ---
#pragma unroll
    for (int i = 0; i < 8; ++i) {
        const int row = row0 + ty * 8 + i;
#pragma unroll
        for (int j = 0; j < 8; ++j) {
            const int col = col0 + tx * 8 + j;
            if (col < N) {
                float v = acc[i][j];
                if (bias) v += bias[col];
                if (col >= special_col)
                    aux[(size_t)row * 2 + (col - special_col)] = v;
                else
                    C[(size_t)row * ldc + col] = v;
            }
        }
    }
}

// ---------------------------------------------------------------------------
// Per-row softmax stats: one workgroup per row. Online (max, sumexp) per
// thread, LDS tree combine. Segments: root [0,2000)+2 extras, c0 [2000,10000),
// c1 [10000,50257). stats[r*8] = {rm, rlse, m0, lse0, m1, lse1, clp0, clp1}.
// ---------------------------------------------------------------------------
__global__ __launch_bounds__(256)
void row_stats(const float* __restrict__ out, const float* __restrict__ root2,
               float* __restrict__ stats)
{
    __shared__ float sm[256], ss[256];
    const int r = blockIdx.x, t = threadIdx.x;
    const float* rowp = out + (size_t)r * VOCAB;

    float M[3], L[3];
    const int beg[3] = {0, CUT0, CUT1};
    const int len[3] = {CUT0, CUT1 - CUT0, VOCAB - CUT1};

    for (int sg = 0; sg < 3; ++sg) {
        float m = -1e30f, s = 0.f;
        const float* p = rowp + beg[sg];
        for (int i = t; i < len[sg]; i += 256) {
            float v = p[i];
            if (v > m) { s = s * __expf(m - v) + 1.f; m = v; }
            else       { s += __expf(v - m); }
        }
        if (sg == 0 && t < 2) {   // fold the 2 cluster logits into root segment
            float v = root2[r * 2 + t];
            if (v > m) { s = s * __expf(m - v) + 1.f; m = v; }
            else       { s += __expf(v - m); }
        }
        sm[t] = m; ss[t] = s;
        __syncthreads();
        for (int w = 128; w > 0; w >>= 1) {
            if (t < w) {
                float m1 = sm[t], s1 = ss[t];
                float m2 = sm[t + w], s2 = ss[t + w];
                float mm = fmaxf(m1, m2);
                sm[t] = mm;
                ss[t] = s1 * __expf(m1 - mm) + s2 * __expf(m2 - mm);
            }
            __syncthreads();
        }
        M[sg] = sm[0]; L[sg] = logf(ss[0]);
        __syncthreads();
    }

    if (t == 0) {
        float* st = stats + r * 8;
        st[0] = M[0]; st[1] = L[0];
        st[2] = M[1]; st[3] = L[1];
        st[4] = M[2]; st[5] = L[2];
        st[6] = root2[r * 2 + 0] - M[0] - L[0];
        st[7] = root2[r * 2 + 1] - M[0] - L[0];
    }
}

// ---------------------------------------------------------------------------
// In-place finalize: out = exp(logit - m - lse + cluster_logprob)
// ---------------------------------------------------------------------------
__global__ __launch_bounds__(256)
void finalize(float* __restrict__ out, const float* __restrict__ stats)
{
    const int r = blockIdx.y;
    const float* st = stats + r * 8;
    const float rm = st[0], rl = st[1];
    const float m0 = st[2], l0 = st[3];
    const float m1 = st[4], l1 = st[5];
    const float clp0 = st[6], clp1 = st[7];
    const size_t ro = (size_t)r * VOCAB;

    int v = blockIdx.x * 2048 + threadIdx.x;
#pragma unroll
    for (int it = 0; it < 8; ++it, v += 256) {
        if (v < VOCAB) {
            float l = out[ro + v];
            float p;
            if (v < CUT0)      p = __expf(l - rm - rl);
            else if (v < CUT1) p = __expf(l - m0 - l0 + clp0);
            else               p = __expf(l - m1 - l1 + clp1);
            out[ro + v] = p;
        }
    }
}

// ---------------------------------------------------------------------------
extern "C" void kernel_launch(void* const* d_in, const int* in_sizes, int n_in,
                              void* d_out, int out_size, void* d_ws, size_t ws_size,
                              hipStream_t stream)
{
    (void)in_sizes; (void)n_in; (void)out_size; (void)ws_size;

    const float* x    = (const float*)d_in[0];
    // d_in[1] = targets (unused by the reference output)
    const float* head = (const float*)d_in[2];
    const float* pk0  = (const float*)d_in[3];
    const float* pb0  = (const float*)d_in[4];
    const float* sk0  = (const float*)d_in[5];
    const float* sb0  = (const float*)d_in[6];
    const float* pk1  = (const float*)d_in[7];
    const float* pb1  = (const float*)d_in[8];
    const float* sk1  = (const float*)d_in[9];
    const float* sb1  = (const float*)d_in[10];

    float* out = (float*)d_out;
    float* ws  = (float*)d_ws;

    float* h0    = ws;                    // 2048*256 f32
    float* h1    = h0 + ROWS * 256;       // 2048*64
    float* root2 = h1 + ROWS * 64;        // 2048*2
    float* stats = root2 + ROWS * 2;      // 2048*8

    const dim3 blk(256);
    const int NOSPECIAL = 1 << 30;

    // root logits -> out[:, :2000]; cols 2000/2001 -> root2
    gemm_f32<<<dim3(16, 16), blk, 0, stream>>>(x, head, nullptr, out, root2,
                                               ROWS, 2002, DIM, VOCAB, 2000);
    // h0 = x @ pk0 + pb0
    gemm_f32<<<dim3(2, 16), blk, 0, stream>>>(x, pk0, pb0, h0, nullptr,
                                              ROWS, 256, DIM, 256, NOSPECIAL);
    // h1 = x @ pk1 + pb1
    gemm_f32<<<dim3(1, 16), blk, 0, stream>>>(x, pk1, pb1, h1, nullptr,
                                              ROWS, 64, DIM, 64, NOSPECIAL);
    // logits0 = h0 @ sk0 + sb0 -> out[:, 2000:10000]
    gemm_f32<<<dim3(63, 16), blk, 0, stream>>>(h0, sk0, sb0, out + CUT0, nullptr,
                                               ROWS, 8000, 256, VOCAB, NOSPECIAL);
    // logits1 = h1 @ sk1 + sb1 -> out[:, 10000:50257]
    gemm_f32<<<dim3(315, 16), blk, 0, stream>>>(h1, sk1, sb1, out + CUT1, nullptr,
                                                ROWS, 40257, 64, VOCAB, NOSPECIAL);

    row_stats<<<dim3(ROWS), blk, 0, stream>>>(out, root2, stats);
    finalize<<<dim3(25, ROWS), blk, 0, stream>>>(out, stats);
}

// Round 2
// 637.328 us; speedup vs baseline: 2.3403x; 2.3403x over previous
//
#include <hip/hip_runtime.h>
#include <cstdint>
#include <cstddef>

#define ROWS   2048
#define DIM    1024
#define VOCAB  50257
#define CUT0   2000
#define CUT1   10000

typedef __attribute__((ext_vector_type(8))) __bf16 bf16x8;
typedef __attribute__((ext_vector_type(4))) float  f32x4;

__device__ __forceinline__ ushort f2bf(float f) {
    uint32_t u = __float_as_uint(f);
    uint32_t r = (u + 0x7fffu + ((u >> 16) & 1u)) >> 16;
    return (ushort)r;
}
__device__ __forceinline__ float bf2f(ushort h) {
    return __uint_as_float(((uint32_t)h) << 16);
}

__device__ __forceinline__ void gload_lds16(const void* g, void* l) {
    __builtin_amdgcn_global_load_lds(
        (const __attribute__((address_space(1))) void*)g,
        (__attribute__((address_space(3))) void*)l, 16, 0, 0);
}

// ---------------------------------------------------------------------------
// convert_x: x[2048,1024] f32 -> A2[2048, 3072] bf16 per-row [hi | lo | hi]
// ---------------------------------------------------------------------------
__global__ __launch_bounds__(256)
void convert_x(const float* __restrict__ x, ushort* __restrict__ A2)
{
    int fid  = blockIdx.x * 256 + threadIdx.x;   // 524288 float4s
    int mrow = fid >> 8;                         // 256 float4 per row
    int kq   = fid & 255;
    float4 v = ((const float4*)x)[fid];
    ushort4 hi, lo;
    hi.x = f2bf(v.x); lo.x = f2bf(v.x - bf2f(hi.x));
    hi.y = f2bf(v.y); lo.y = f2bf(v.y - bf2f(hi.y));
    hi.z = f2bf(v.z); lo.z = f2bf(v.z - bf2f(hi.z));
    hi.w = f2bf(v.w); lo.w = f2bf(v.w - bf2f(hi.w));
    size_t base = (size_t)mrow * 3072 + kq * 4;
    *(ushort4*)(A2 + base)        = hi;
    *(ushort4*)(A2 + base + 1024) = lo;
    *(ushort4*)(A2 + base + 2048) = hi;
}

// ---------------------------------------------------------------------------
// convert_wT: W[K,N] f32 -> WT2[Npad, 3K] bf16, row n holds [hi | hi | lo] of
// W[:,n]. Rows n>=N zero-filled. 32x32 LDS transpose.
// ---------------------------------------------------------------------------
__global__ __launch_bounds__(256)
void convert_wT(const float* __restrict__ W, ushort* __restrict__ WT2,
                int K, int N)
{
    __shared__ float tile[32][33];
    int tx = threadIdx.x & 31, ty = threadIdx.x >> 5;
    int n0 = blockIdx.x * 32, k0 = blockIdx.y * 32;
#pragma unroll
    for (int i = 0; i < 4; ++i) {
        int kk = ty + i * 8;
        int n  = n0 + tx;
        tile[kk][tx] = (n < N) ? W[(size_t)(k0 + kk) * N + n] : 0.f;
    }
    __syncthreads();
#pragma unroll
    for (int i = 0; i < 4; ++i) {
        int nn = ty + i * 8;
        int r  = n0 + nn;
        float v = tile[tx][nn];
        ushort hi = f2bf(v);
        ushort lo = f2bf(v - bf2f(hi));
        size_t rb = (size_t)r * (3 * K) + k0 + tx;
        WT2[rb]         = hi;
        WT2[rb + K]     = hi;
        WT2[rb + 2 * K] = lo;
    }
}

// ---------------------------------------------------------------------------
// Unified bf16 MFMA GEMM, NT form: C[M,N] = A2[M,Kp] . B2T[N,Kp]^T
// 128x128 tile, BK=64, 256 threads (4 waves, 2x2), mfma_f32_16x16x32_bf16.
// global_load_lds staging with XOR-swizzled per-lane source (rule #21).
// MODE 0: root logits  -> out cols [0,2000) + aux(2 cluster logits) + partials
// MODE 1: scale logits -> out cols colOffset+  + bias + partials
// MODE 3: proj         -> h2 triple-bf16 [hi|lo|hi] + bias
// ---------------------------------------------------------------------------
template<int MODE>
__global__ __launch_bounds__(256)
void gemm_bf16(const ushort* __restrict__ A, const ushort* __restrict__ B,
               const float* __restrict__ bias, float* __restrict__ out,
               float* __restrict__ aux, float2* __restrict__ partials,
               ushort* __restrict__ h2,
               int Kp, int Nvalid, int colOffset, int K2)
{
    __shared__ ushort As[128 * 64];
    __shared__ ushort Bs[128 * 64];

    const int t    = threadIdx.x;
    const int lane = t & 63;
    const int w    = t >> 6;
    const int wr   = w >> 1, wc = w & 1;
    const int q    = lane >> 4, cl = lane & 15;
    const int row0blk = blockIdx.y * 128;
    const int col0blk = blockIdx.x * 128;

    f32x4 acc[4][4];
#pragma unroll
    for (int m = 0; m < 4; ++m)
#pragma unroll
        for (int n = 0; n < 4; ++n)
            acc[m][n] = (f32x4){0.f, 0.f, 0.f, 0.f};

    for (int k0 = 0; k0 < Kp; k0 += 64) {
        __syncthreads();
        // stage A tile (128 rows x 64 k) and B tile, 4 issues each, 16B/lane
#pragma unroll
        for (int iss = 0; iss < 4; ++iss) {
            int ci  = iss * 256 + w * 64 + lane;
            int row = ci >> 3;
            int ch  = (ci & 7) ^ (row & 7);     // inverse swizzle on source
            gload_lds16(A + (size_t)(row0blk + row) * Kp + k0 + ch * 8,
                        As + (size_t)(iss * 256 + w * 64) * 8);
            gload_lds16(B + (size_t)(col0blk + row) * Kp + k0 + ch * 8,
                        Bs + (size_t)(iss * 256 + w * 64) * 8);
        }
        __syncthreads();

#pragma unroll
        for (int kk = 0; kk < 2; ++kk) {
            bf16x8 a[4], b[4];
#pragma unroll
            for (int m = 0; m < 4; ++m) {
                int row = wr * 64 + m * 16 + cl;
                int ch  = (kk * 4 + q) ^ (row & 7);   // swizzled read
                a[m] = *(const bf16x8*)(As + row * 64 + ch * 8);
            }
#pragma unroll
            for (int n = 0; n < 4; ++n) {
                int row = wc * 64 + n * 16 + cl;
                int ch  = (kk * 4 + q) ^ (row & 7);
                b[n] = *(const bf16x8*)(Bs + row * 64 + ch * 8);
            }
#pragma unroll
            for (int m = 0; m < 4; ++m)
#pragma unroll
                for (int n = 0; n < 4; ++n)
                    acc[m][n] = __builtin_amdgcn_mfma_f32_16x16x32_bf16(
                        a[m], b[n], acc[m][n], 0, 0, 0);
        }
    }
    __syncthreads();   // LDS reads done; safe to reuse As for reductions

    if (MODE == 3) {
        // proj epilogue: h = acc + bias -> triple bf16 [hi | lo | hi]
#pragma unroll
        for (int m = 0; m < 4; ++m)
#pragma unroll
            for (int n = 0; n < 4; ++n) {
                int colseg = col0blk + wc * 64 + n * 16 + cl;
                if (colseg < K2) {
                    float bv = bias[colseg];
#pragma unroll
                    for (int j = 0; j < 4; ++j) {
                        int rg = row0blk + wr * 64 + m * 16 + q * 4 + j;
                        float h = acc[m][n][j] + bv;
                        ushort hi = f2bf(h);
                        ushort lo = f2bf(h - bf2f(hi));
                        size_t rb = (size_t)rg * (3 * K2);
                        h2[rb + colseg]          = hi;
                        h2[rb + K2 + colseg]     = lo;
                        h2[rb + 2 * K2 + colseg] = hi;
                    }
                }
            }
        return;
    }

    // logits epilogue: store + per-row partial (max, sumexp) over this tile
    float bn[4];
#pragma unroll
    for (int n = 0; n < 4; ++n) {
        int colseg = col0blk + wc * 64 + n * 16 + cl;
        bn[n] = (MODE == 1 && colseg < Nvalid) ? bias[colseg] : 0.f;
    }

    float* sred = (float*)As;   // [smax: 2x128][ssum: 2x128]

#pragma unroll
    for (int m = 0; m < 4; ++m)
#pragma unroll
        for (int j = 0; j < 4; ++j) {
            int rloc = wr * 64 + m * 16 + q * 4 + j;
            int rg   = row0blk + rloc;
            float vv[4];
            float mx = -1e30f;
#pragma unroll
            for (int n = 0; n < 4; ++n) {
                int colseg = col0blk + wc * 64 + n * 16 + cl;
                float v = acc[m][n][j] + bn[n];
                bool ok = colseg < Nvalid;
                if (ok) {
                    if (MODE == 0 && colseg >= CUT0)
                        aux[rg * 2 + (colseg - CUT0)] = v;
                    else
                        out[(size_t)rg * VOCAB + colOffset + colseg] = v;
                }
                vv[n] = ok ? v : -1e30f;
                mx = fmaxf(mx, vv[n]);
            }
            float sm = 0.f;
#pragma unroll
            for (int n = 0; n < 4; ++n) sm += __expf(vv[n] - mx);
            // combine across the 16 lanes (cl) sharing this row
#pragma unroll
            for (int d = 1; d < 16; d <<= 1) {
                float om = __shfl_xor(mx, d);
                float os = __shfl_xor(sm, d);
                float nm = fmaxf(mx, om);
                sm = sm * __expf(mx - nm) + os * __expf(om - nm);
                mx = nm;
            }
            if (cl == 0) {
                sred[wc * 128 + rloc]       = mx;
                sred[256 + wc * 128 + rloc] = sm;
            }
        }
    __syncthreads();
    if (t < 128) {
        float m1 = sred[t],       m2 = sred[128 + t];
        float s1 = sred[256 + t], s2 = sred[384 + t];
        float mm = fmaxf(m1, m2);
        float ss = s1 * __expf(m1 - mm) + s2 * __expf(m2 - mm);
        partials[(size_t)blockIdx.x * ROWS + row0blk + t] = make_float2(mm, ss);
    }
}

// ---------------------------------------------------------------------------
// reduce per-row partials -> stats[r] = {C_root, C_seg1, C_seg2, 0}
// where p = exp(logit - C_seg)
// ---------------------------------------------------------------------------
__global__ __launch_bounds__(256)
void reduce_stats(const float2* __restrict__ P0, const float2* __restrict__ P1,
                  const float2* __restrict__ P2, const float* __restrict__ root2,
                  float* __restrict__ stats)
{
    __shared__ float sm[256], ss[256];
    const int r = blockIdx.x, t = threadIdx.x;
    const float2* Ps[3] = {P0, P1, P2};
    const int cnt[3] = {16, 63, 315};
    float M[3], L[3];

    for (int sg = 0; sg < 3; ++sg) {
        float m = -1e30f, s = 0.f;
        for (int i = t; i < cnt[sg]; i += 256) {
            float2 p = Ps[sg][(size_t)i * ROWS + r];
            float mm = fmaxf(m, p.x);
            s = s * __expf(m - mm) + p.y * __expf(p.x - mm);
            m = mm;
        }
        sm[t] = m; ss[t] = s;
        __syncthreads();
        for (int w2 = 128; w2 > 0; w2 >>= 1) {
            if (t < w2) {
                float m1 = sm[t], m2 = sm[t + w2];
                float s1 = ss[t], s2 = ss[t + w2];
                float mm = fmaxf(m1, m2);
                sm[t] = mm;
                ss[t] = s1 * __expf(m1 - mm) + s2 * __expf(m2 - mm);
            }
            __syncthreads();
        }
        M[sg] = sm[0]; L[sg] = logf(ss[0]);
        __syncthreads();
    }

    if (t == 0) {
        float rm = M[0], rl = L[0];
        float clp0 = root2[r * 2 + 0] - rm - rl;
        float clp1 = root2[r * 2 + 1] - rm - rl;
        float4 st;
        st.x = rm + rl;            // root
        st.y = M[1] + L[1] - clp0; // cluster 0
        st.z = M[2] + L[2] - clp1; // cluster 1
        st.w = 0.f;
        ((float4*)stats)[r] = st;
    }
}

// ---------------------------------------------------------------------------
// finalize: out = exp(logit - C_seg), flat float4 pass
// ---------------------------------------------------------------------------
__global__ __launch_bounds__(256)
void finalize(float* __restrict__ out, const float4* __restrict__ stats)
{
    size_t i4 = (size_t)blockIdx.x * 256 + threadIdx.x;
    float4 v = ((float4*)out)[i4];
    uint32_t e0 = (uint32_t)(i4 * 4);
    float r4[4] = {v.x, v.y, v.z, v.w};
#pragma unroll
    for (int j = 0; j < 4; ++j) {
        uint32_t e = e0 + j;
        uint32_t r = e / VOCAB;
        uint32_t c = e - r * VOCAB;
        float4 st = stats[r];
        float C = (c < CUT0) ? st.x : ((c < CUT1) ? st.y : st.z);
        r4[j] = __expf(r4[j] - C);
    }
    v.x = r4[0]; v.y = r4[1]; v.z = r4[2]; v.w = r4[3];
    ((float4*)out)[i4] = v;
}

// ---------------------------------------------------------------------------
extern "C" void kernel_launch(void* const* d_in, const int* in_sizes, int n_in,
                              void* d_out, int out_size, void* d_ws, size_t ws_size,
                              hipStream_t stream)
{
    (void)in_sizes; (void)n_in; (void)out_size; (void)ws_size;

    const float* x    = (const float*)d_in[0];
    const float* head = (const float*)d_in[2];
    const float* pk0  = (const float*)d_in[3];
    const float* pb0  = (const float*)d_in[4];
    const float* sk0  = (const float*)d_in[5];
    const float* sb0  = (const float*)d_in[6];
    const float* pk1  = (const float*)d_in[7];
    const float* pb1  = (const float*)d_in[8];
    const float* sk1  = (const float*)d_in[9];
    const float* sb1  = (const float*)d_in[10];

    float* out = (float*)d_out;
    char*  ws  = (char*)d_ws;

    // ws layout (bytes)
    ushort* A2     = (ushort*)(ws);                    // 2048x3072
    ushort* headT2 = (ushort*)(ws + 12582912);         // 2048x3072
    ushort* pk0T2  = (ushort*)(ws + 25165824);         // 256x3072
    ushort* pk1T2  = (ushort*)(ws + 26738688);         // 128x3072
    ushort* sk0T2  = (ushort*)(ws + 27525120);         // 8064x768
    ushort* sk1T2  = (ushort*)(ws + 39911424);         // 40320x192
    ushort* h2_0   = (ushort*)(ws + 55394304);         // 2048x768
    ushort* h2_1   = (ushort*)(ws + 58540032);         // 2048x192
    float*  root2  = (float*)(ws + 59326464);          // 2048x2
    float2* P0     = (float2*)(ws + 59342848);         // 16x2048
    float2* P1     = (float2*)(ws + 59604992);         // 63x2048
    float2* P2     = (float2*)(ws + 60637184);         // 315x2048
    float*  stats  = (float*)(ws + 65798144);          // 2048x4

    const dim3 blk(256);

    // conversions
    convert_x<<<dim3(2048), blk, 0, stream>>>(x, A2);
    convert_wT<<<dim3(64, 32),   blk, 0, stream>>>(head, headT2, 1024, 2002);
    convert_wT<<<dim3(8, 32),    blk, 0, stream>>>(pk0, pk0T2, 1024, 256);
    convert_wT<<<dim3(4, 32),    blk, 0, stream>>>(pk1, pk1T2, 1024, 64);
    convert_wT<<<dim3(252, 8),   blk, 0, stream>>>(sk0, sk0T2, 256, 8000);
    convert_wT<<<dim3(1260, 2),  blk, 0, stream>>>(sk1, sk1T2, 64, 40257);

    // projections: h2 = triple-bf16(x @ pk + pb)
    gemm_bf16<3><<<dim3(2, 16), blk, 0, stream>>>(A2, pk0T2, pb0, nullptr,
        nullptr, nullptr, h2_0, 3072, 256, 0, 256);
    gemm_bf16<3><<<dim3(1, 16), blk, 0, stream>>>(A2, pk1T2, pb1, nullptr,
        nullptr, nullptr, h2_1, 3072, 64, 0, 64);

    // root logits -> out[:, :2000] (+aux cluster logits) + partials P0
    gemm_bf16<0><<<dim3(16, 16), blk, 0, stream>>>(A2, headT2, nullptr, out,
        root2, P0, nullptr, 3072, 2002, 0, 0);
    // scale0 logits -> out[:, 2000:10000] + partials P1
    gemm_bf16<1><<<dim3(63, 16), blk, 0, stream>>>(h2_0, sk0T2, sb0, out,
        nullptr, P1, nullptr, 768, 8000, CUT0, 0);
    // scale1 logits -> out[:, 10000:50257] + partials P2
    gemm_bf16<1><<<dim3(315, 16), blk, 0, stream>>>(h2_1, sk1T2, sb1, out,
        nullptr, P2, nullptr, 192, 40257, CUT1, 0);

    reduce_stats<<<dim3(ROWS), blk, 0, stream>>>(P0, P1, P2, root2, stats);
    finalize<<<dim3(100514), blk, 0, stream>>>(out, (const float4*)stats);
}

// Round 3
// 633.382 us; speedup vs baseline: 2.3548x; 1.0062x over previous
//
#include <hip/hip_runtime.h>
#include <hip/hip_fp16.h>
#include <cstdint>
#include <cstddef>

#define ROWS   2048
#define DIM    1024
#define VOCAB  50257
#define CUT0   2000
#define CUT1   10000

typedef __attribute__((ext_vector_type(8))) __bf16 bf16x8;
typedef __attribute__((ext_vector_type(4))) float  f32x4;

__device__ __forceinline__ ushort f2bf(float f) {
    uint32_t u = __float_as_uint(f);
    uint32_t r = (u + 0x7fffu + ((u >> 16) & 1u)) >> 16;
    return (ushort)r;
}
__device__ __forceinline__ float bf2f(ushort h) {
    return __uint_as_float(((uint32_t)h) << 16);
}

__device__ __forceinline__ void gload_lds16(const void* g, void* l) {
    __builtin_amdgcn_global_load_lds(
        (const __attribute__((address_space(1))) void*)g,
        (__attribute__((address_space(3))) void*)l, 16, 0, 0);
}

// ---------------------------------------------------------------------------
// convert_x: x[2048,1024] f32 -> A2[2048, 3072] bf16 per-row [hi | lo | hi]
// ---------------------------------------------------------------------------
__global__ __launch_bounds__(256)
void convert_x(const float* __restrict__ x, ushort* __restrict__ A2)
{
    int fid  = blockIdx.x * 256 + threadIdx.x;   // 524288 float4s
    int mrow = fid >> 8;                         // 256 float4 per row
    int kq   = fid & 255;
    float4 v = ((const float4*)x)[fid];
    ushort4 hi, lo;
    hi.x = f2bf(v.x); lo.x = f2bf(v.x - bf2f(hi.x));
    hi.y = f2bf(v.y); lo.y = f2bf(v.y - bf2f(hi.y));
    hi.z = f2bf(v.z); lo.z = f2bf(v.z - bf2f(hi.z));
    hi.w = f2bf(v.w); lo.w = f2bf(v.w - bf2f(hi.w));
    size_t base = (size_t)mrow * 3072 + kq * 4;
    *(ushort4*)(A2 + base)        = hi;
    *(ushort4*)(A2 + base + 1024) = lo;
    *(ushort4*)(A2 + base + 2048) = hi;
}

// ---------------------------------------------------------------------------
// convert_wT: W[K,N] f32 -> WT2[Npad, 3K] bf16, row n holds [hi | hi | lo] of
// W[:,n]. Rows n>=N zero-filled. 32x32 LDS transpose.
// ---------------------------------------------------------------------------
__global__ __launch_bounds__(256)
void convert_wT(const float* __restrict__ W, ushort* __restrict__ WT2,
                int K, int N)
{
    __shared__ float tile[32][33];
    int tx = threadIdx.x & 31, ty = threadIdx.x >> 5;
    int n0 = blockIdx.x * 32, k0 = blockIdx.y * 32;
#pragma unroll
    for (int i = 0; i < 4; ++i) {
        int kk = ty + i * 8;
        int n  = n0 + tx;
        tile[kk][tx] = (n < N) ? W[(size_t)(k0 + kk) * N + n] : 0.f;
    }
    __syncthreads();
#pragma unroll
    for (int i = 0; i < 4; ++i) {
        int nn = ty + i * 8;
        int r  = n0 + nn;
        float v = tile[tx][nn];
        ushort hi = f2bf(v);
        ushort lo = f2bf(v - bf2f(hi));
        size_t rb = (size_t)r * (3 * K) + k0 + tx;
        WT2[rb]         = hi;
        WT2[rb + K]     = hi;
        WT2[rb + 2 * K] = lo;
    }
}

// ---------------------------------------------------------------------------
// Unified bf16 MFMA GEMM, NT form: C[M,N] = A2[M,Kp] . B2T[N,Kp]^T
// 128x128 tile, BK=64, 256 threads (4 waves, 2x2), mfma_f32_16x16x32_bf16.
// global_load_lds staging with XOR-swizzled per-lane source (rule #21).
// MODE 0: root  -> lgt cols [0,2000) fp16 + aux(2 cluster logits) + partials
// MODE 1: scale -> lgt cols colOffset+ fp16 + bias + partials
// MODE 3: proj  -> h2 triple-bf16 [hi|lo|hi] + bias
// ---------------------------------------------------------------------------
template<int MODE>
__global__ __launch_bounds__(256)
void gemm_bf16(const ushort* __restrict__ A, const ushort* __restrict__ B,
               const float* __restrict__ bias, __half* __restrict__ lgt,
               float* __restrict__ aux, float2* __restrict__ partials,
               ushort* __restrict__ h2,
               int Kp, int Nvalid, int colOffset, int K2, int nTiles)
{
    __shared__ ushort As[128 * 64];
    __shared__ ushort Bs[128 * 64];

    const int t    = threadIdx.x;
    const int lane = t & 63;
    const int w    = t >> 6;
    const int wr   = w >> 1, wc = w & 1;
    const int q    = lane >> 4, cl = lane & 15;
    const int row0blk = blockIdx.y * 128;
    const int col0blk = blockIdx.x * 128;

    f32x4 acc[4][4];
#pragma unroll
    for (int m = 0; m < 4; ++m)
#pragma unroll
        for (int n = 0; n < 4; ++n)
            acc[m][n] = (f32x4){0.f, 0.f, 0.f, 0.f};

    for (int k0 = 0; k0 < Kp; k0 += 64) {
        __syncthreads();
#pragma unroll
        for (int iss = 0; iss < 4; ++iss) {
            int ci  = iss * 256 + w * 64 + lane;
            int row = ci >> 3;
            int ch  = (ci & 7) ^ (row & 7);     // inverse swizzle on source
            gload_lds16(A + (size_t)(row0blk + row) * Kp + k0 + ch * 8,
                        As + (size_t)(iss * 256 + w * 64) * 8);
            gload_lds16(B + (size_t)(col0blk + row) * Kp + k0 + ch * 8,
                        Bs + (size_t)(iss * 256 + w * 64) * 8);
        }
        __syncthreads();

#pragma unroll
        for (int kk = 0; kk < 2; ++kk) {
            bf16x8 a[4], b[4];
#pragma unroll
            for (int m = 0; m < 4; ++m) {
                int row = wr * 64 + m * 16 + cl;
                int ch  = (kk * 4 + q) ^ (row & 7);   // swizzled read
                a[m] = *(const bf16x8*)(As + row * 64 + ch * 8);
            }
#pragma unroll
            for (int n = 0; n < 4; ++n) {
                int row = wc * 64 + n * 16 + cl;
                int ch  = (kk * 4 + q) ^ (row & 7);
                b[n] = *(const bf16x8*)(Bs + row * 64 + ch * 8);
            }
#pragma unroll
            for (int m = 0; m < 4; ++m)
#pragma unroll
                for (int n = 0; n < 4; ++n)
                    acc[m][n] = __builtin_amdgcn_mfma_f32_16x16x32_bf16(
                        a[m], b[n], acc[m][n], 0, 0, 0);
        }
    }
    __syncthreads();   // LDS reads done; safe to reuse As for reductions

    if (MODE == 3) {
#pragma unroll
        for (int m = 0; m < 4; ++m)
#pragma unroll
            for (int n = 0; n < 4; ++n) {
                int colseg = col0blk + wc * 64 + n * 16 + cl;
                if (colseg < K2) {
                    float bv = bias[colseg];
#pragma unroll
                    for (int j = 0; j < 4; ++j) {
                        int rg = row0blk + wr * 64 + m * 16 + q * 4 + j;
                        float h = acc[m][n][j] + bv;
                        ushort hi = f2bf(h);
                        ushort lo = f2bf(h - bf2f(hi));
                        size_t rb = (size_t)rg * (3 * K2);
                        h2[rb + colseg]          = hi;
                        h2[rb + K2 + colseg]     = lo;
                        h2[rb + 2 * K2 + colseg] = hi;
                    }
                }
            }
        return;
    }

    // logits epilogue: fp16 store + per-row partial (max, sumexp)
    float bn[4];
#pragma unroll
    for (int n = 0; n < 4; ++n) {
        int colseg = col0blk + wc * 64 + n * 16 + cl;
        bn[n] = (MODE == 1 && colseg < Nvalid) ? bias[colseg] : 0.f;
    }

    float* sred = (float*)As;   // [smax: 2x128][ssum: 2x128]

#pragma unroll
    for (int m = 0; m < 4; ++m)
#pragma unroll
        for (int j = 0; j < 4; ++j) {
            int rloc = wr * 64 + m * 16 + q * 4 + j;
            int rg   = row0blk + rloc;
            float vv[4];
            float mx = -1e30f;
#pragma unroll
            for (int n = 0; n < 4; ++n) {
                int colseg = col0blk + wc * 64 + n * 16 + cl;
                float v = acc[m][n][j] + bn[n];
                bool ok = colseg < Nvalid;
                if (ok) {
                    if (MODE == 0 && colseg >= CUT0)
                        aux[rg * 2 + (colseg - CUT0)] = v;
                    else
                        lgt[(size_t)rg * VOCAB + colOffset + colseg] =
                            __float2half_rn(v);
                }
                vv[n] = ok ? v : -1e30f;
                mx = fmaxf(mx, vv[n]);
            }
            float sm = 0.f;
#pragma unroll
            for (int n = 0; n < 4; ++n) sm += __expf(vv[n] - mx);
#pragma unroll
            for (int d = 1; d < 16; d <<= 1) {
                float om = __shfl_xor(mx, d);
                float os = __shfl_xor(sm, d);
                float nm = fmaxf(mx, om);
                sm = sm * __expf(mx - nm) + os * __expf(om - nm);
                mx = nm;
            }
            if (cl == 0) {
                sred[wc * 128 + rloc]       = mx;
                sred[256 + wc * 128 + rloc] = sm;
            }
        }
    __syncthreads();
    if (t < 128) {
        float m1 = sred[t],       m2 = sred[128 + t];
        float s1 = sred[256 + t], s2 = sred[384 + t];
        float mm = fmaxf(m1, m2);
        float ss = s1 * __expf(m1 - mm) + s2 * __expf(m2 - mm);
        // transposed layout: partials[row][tile] (contiguous per row)
        partials[(size_t)(row0blk + t) * nTiles + blockIdx.x] =
            make_float2(mm, ss);
    }
}

// ---------------------------------------------------------------------------
// reduce per-row partials -> stats[r] = {C_root, C_seg1, C_seg2, 0},
// p = exp(logit - C_seg)
// ---------------------------------------------------------------------------
__global__ __launch_bounds__(256)
void reduce_stats(const float2* __restrict__ P0, const float2* __restrict__ P1,
                  const float2* __restrict__ P2, const float* __restrict__ root2,
                  float* __restrict__ stats)
{
    __shared__ float sm[256], ss[256];
    const int r = blockIdx.x, t = threadIdx.x;
    const float2* Ps[3] = {P0, P1, P2};
    const int cnt[3] = {16, 63, 315};
    float M[3], L[3];

    for (int sg = 0; sg < 3; ++sg) {
        float m = -1e30f, s = 0.f;
        for (int i = t; i < cnt[sg]; i += 256) {
            float2 p = Ps[sg][(size_t)r * cnt[sg] + i];
            float mm = fmaxf(m, p.x);
            s = s * __expf(m - mm) + p.y * __expf(p.x - mm);
            m = mm;
        }
        sm[t] = m; ss[t] = s;
        __syncthreads();
        for (int w2 = 128; w2 > 0; w2 >>= 1) {
            if (t < w2) {
                float m1 = sm[t], m2 = sm[t + w2];
                float s1 = ss[t], s2 = ss[t + w2];
                float mm = fmaxf(m1, m2);
                sm[t] = mm;
                ss[t] = s1 * __expf(m1 - mm) + s2 * __expf(m2 - mm);
            }
            __syncthreads();
        }
        M[sg] = sm[0]; L[sg] = logf(ss[0]);
        __syncthreads();
    }

    if (t == 0) {
        float rm = M[0], rl = L[0];
        float clp0 = root2[r * 2 + 0] - rm - rl;
        float clp1 = root2[r * 2 + 1] - rm - rl;
        float4 st;
        st.x = rm + rl;            // root
        st.y = M[1] + L[1] - clp0; // cluster 0
        st.z = M[2] + L[2] - clp1; // cluster 1
        st.w = 0.f;
        ((float4*)stats)[r] = st;
    }
}

// ---------------------------------------------------------------------------
// finalize: out = exp(lgt_fp16 - C_seg), flat pass: read 4x fp16, write float4
// ---------------------------------------------------------------------------
__global__ __launch_bounds__(256)
void finalize(const __half* __restrict__ lgt, const float4* __restrict__ stats,
              float4* __restrict__ out)
{
    size_t i4 = (size_t)blockIdx.x * 256 + threadIdx.x;
    uint32_t e0 = (uint32_t)(i4 * 4);
    uint2 raw = *(const uint2*)(lgt + e0);
    __half2 hA = __builtin_bit_cast(__half2, raw.x);
    __half2 hB = __builtin_bit_cast(__half2, raw.y);
    float lv[4] = {__half2float(hA.x), __half2float(hA.y),
                   __half2float(hB.x), __half2float(hB.y)};
    float r4[4];
#pragma unroll
    for (int j = 0; j < 4; ++j) {
        uint32_t e = e0 + j;
        uint32_t r = e / (uint32_t)VOCAB;
        uint32_t c = e - r * (uint32_t)VOCAB;
        float4 st = stats[r];
        float C = (c < CUT0) ? st.x : ((c < CUT1) ? st.y : st.z);
        r4[j] = __expf(lv[j] - C);
    }
    out[i4] = make_float4(r4[0], r4[1], r4[2], r4[3]);
}

// ---------------------------------------------------------------------------
extern "C" void kernel_launch(void* const* d_in, const int* in_sizes, int n_in,
                              void* d_out, int out_size, void* d_ws, size_t ws_size,
                              hipStream_t stream)
{
    (void)in_sizes; (void)n_in; (void)out_size; (void)ws_size;

    const float* x    = (const float*)d_in[0];
    const float* head = (const float*)d_in[2];
    const float* pk0  = (const float*)d_in[3];
    const float* pb0  = (const float*)d_in[4];
    const float* sk0  = (const float*)d_in[5];
    const float* sb0  = (const float*)d_in[6];
    const float* pk1  = (const float*)d_in[7];
    const float* pb1  = (const float*)d_in[8];
    const float* sk1  = (const float*)d_in[9];
    const float* sb1  = (const float*)d_in[10];

    float* out = (float*)d_out;
    char*  ws  = (char*)d_ws;

    // ws layout (bytes)
    __half* lgt    = (__half*)(ws);                    // 2048x50257 fp16 (206MB)
    ushort* A2     = (ushort*)(ws + 205852672);        // 2048x3072
    ushort* headT2 = (ushort*)(ws + 218435584);        // 2048x3072
    ushort* pk0T2  = (ushort*)(ws + 231018496);        // 256x3072
    ushort* pk1T2  = (ushort*)(ws + 232591360);        // 128x3072
    ushort* sk0T2  = (ushort*)(ws + 233377792);        // 8064x768
    ushort* sk1T2  = (ushort*)(ws + 245764096);        // 40320x192
    ushort* h2_0   = (ushort*)(ws + 261246976);        // 2048x768
    ushort* h2_1   = (ushort*)(ws + 264392704);        // 2048x192
    float*  root2  = (float*)(ws + 265179136);         // 2048x2
    float2* P0     = (float2*)(ws + 265195520);        // 2048x16
    float2* P1     = (float2*)(ws + 265457664);        // 2048x63
    float2* P2     = (float2*)(ws + 266489856);        // 2048x315
    float*  stats  = (float*)(ws + 271650816);         // 2048x4

    const dim3 blk(256);

    // conversions
    convert_x<<<dim3(2048), blk, 0, stream>>>(x, A2);
    convert_wT<<<dim3(64, 32),   blk, 0, stream>>>(head, headT2, 1024, 2002);
    convert_wT<<<dim3(8, 32),    blk, 0, stream>>>(pk0, pk0T2, 1024, 256);
    convert_wT<<<dim3(4, 32),    blk, 0, stream>>>(pk1, pk1T2, 1024, 64);
    convert_wT<<<dim3(252, 8),   blk, 0, stream>>>(sk0, sk0T2, 256, 8000);
    convert_wT<<<dim3(1260, 2),  blk, 0, stream>>>(sk1, sk1T2, 64, 40257);

    // projections: h2 = triple-bf16(x @ pk + pb)
    gemm_bf16<3><<<dim3(2, 16), blk, 0, stream>>>(A2, pk0T2, pb0, nullptr,
        nullptr, nullptr, h2_0, 3072, 256, 0, 256, 0);
    gemm_bf16<3><<<dim3(1, 16), blk, 0, stream>>>(A2, pk1T2, pb1, nullptr,
        nullptr, nullptr, h2_1, 3072, 64, 0, 64, 0);

    // root logits -> lgt[:, :2000] (+aux cluster logits) + partials P0
    gemm_bf16<0><<<dim3(16, 16), blk, 0, stream>>>(A2, headT2, nullptr, lgt,
        root2, P0, nullptr, 3072, 2002, 0, 0, 16);
    // scale0 logits -> lgt[:, 2000:10000] + partials P1
    gemm_bf16<1><<<dim3(63, 16), blk, 0, stream>>>(h2_0, sk0T2, sb0, lgt,
        nullptr, P1, nullptr, 768, 8000, CUT0, 0, 63);
    // scale1 logits -> lgt[:, 10000:50257] + partials P2
    gemm_bf16<1><<<dim3(315, 16), blk, 0, stream>>>(h2_1, sk1T2, sb1, lgt,
        nullptr, P2, nullptr, 192, 40257, CUT1, 0, 315);

    reduce_stats<<<dim3(ROWS), blk, 0, stream>>>(P0, P1, P2, root2, stats);
    finalize<<<dim3(100514), blk, 0, stream>>>(lgt, (const float4*)stats,
                                               (float4*)out);
}

// Round 4
// 425.735 us; speedup vs baseline: 3.5034x; 1.4877x over previous
//
#include <hip/hip_runtime.h>
#include <cstdint>
#include <cstddef>

#define ROWS   2048
#define DIM    1024
#define VOCAB  50257
#define CUT0   2000
#define CUT1   10000
#define PROJ_LD 320   // h columns: 256 (cluster0) + 64 (cluster1)

typedef __attribute__((ext_vector_type(8))) _Float16 f16x8;
typedef __attribute__((ext_vector_type(4))) float    f32x4;

__device__ __forceinline__ void gload_lds16(const void* g, void* l) {
    __builtin_amdgcn_global_load_lds(
        (const __attribute__((address_space(1))) void*)g,
        (__attribute__((address_space(3))) void*)l, 16, 0, 0);
}

// ---------------------------------------------------------------------------
// convert_all: one kernel, blockIdx.x ranges select the job.
//   [0,2048)     : x f32 -> A f16 flat cast (2048x1024)
//   [2048,4096)  : head  [1024,2002] -> headT [2048,1024]
//   [4096,4352)  : pk0   [1024,256]  -> pkT rows [0,256)
//   [4352,4480)  : pk1   [1024,64]   -> pkT rows [256,384) (pad zero)
//   [4480,6496)  : sk0   [256,8000]  -> sk0T [8064,256]
//   [6496,9016)  : sk1   [64,40257]  -> sk1T [40320,64]
// ---------------------------------------------------------------------------
__global__ __launch_bounds__(256)
void convert_all(const float* __restrict__ x, const float* __restrict__ head,
                 const float* __restrict__ pk0, const float* __restrict__ pk1,
                 const float* __restrict__ sk0, const float* __restrict__ sk1,
                 _Float16* __restrict__ A, _Float16* __restrict__ headT,
                 _Float16* __restrict__ pkT, _Float16* __restrict__ sk0T,
                 _Float16* __restrict__ sk1T)
{
    __shared__ float tile[32][33];
    const int bid = blockIdx.x, t = threadIdx.x;

    if (bid < 2048) {                       // flat cast of x
        int fid = bid * 256 + t;            // float4 index
        float4 v = ((const float4*)x)[fid];
        union { _Float16 h[4]; ushort4 u; } cv;
        cv.h[0] = (_Float16)v.x; cv.h[1] = (_Float16)v.y;
        cv.h[2] = (_Float16)v.z; cv.h[3] = (_Float16)v.w;
        ((ushort4*)A)[fid] = cv.u;
        return;
    }

    const float* src; _Float16* dst; int K, N, local, ntiles;
    if (bid < 4096)      { src = head; dst = headT;          K = 1024; N = 2002;  local = bid - 2048; ntiles = 64;  }
    else if (bid < 4352) { src = pk0;  dst = pkT;            K = 1024; N = 256;   local = bid - 4096; ntiles = 8;   }
    else if (bid < 4480) { src = pk1;  dst = pkT + 256*1024; K = 1024; N = 64;    local = bid - 4352; ntiles = 4;   }
    else if (bid < 6496) { src = sk0;  dst = sk0T;           K = 256;  N = 8000;  local = bid - 4480; ntiles = 252; }
    else                 { src = sk1;  dst = sk1T;           K = 64;   N = 40257; local = bid - 6496; ntiles = 1260;}

    const int bn = local % ntiles, bk = local / ntiles;
    const int tx = t & 31, ty = t >> 5;
    const int n0 = bn * 32, k0 = bk * 32;
#pragma unroll
    for (int i = 0; i < 4; ++i) {
        int kk = ty + i * 8;
        int n  = n0 + tx;
        tile[kk][tx] = (n < N) ? src[(size_t)(k0 + kk) * N + n] : 0.f;
    }
    __syncthreads();
#pragma unroll
    for (int i = 0; i < 4; ++i) {
        int nn = ty + i * 8;
        int r  = n0 + nn;
        dst[(size_t)r * K + k0 + tx] = (_Float16)tile[tx][nn];
    }
}

// ---------------------------------------------------------------------------
// fp16 MFMA GEMM, NT: C[M,N] = A[M,K](lda) . B[Npad,K]^T
// 128x128 tile, BK=64, 256 threads (4 waves 2x2), mfma_f32_16x16x32_f16.
// global_load_lds, XOR-swizzled source + swizzled ds_read (rule #21).
// MODE 0: root  -> lgt[:, 0:2000) f16 + aux cluster logits (f32) + partials
// MODE 1: scale -> lgt[:, colOffset+) f16 + bias + partials
// MODE 3: proj  -> h[2048,320] f16 + split bias (pb0|pb1)
// ---------------------------------------------------------------------------
template<int MODE>
__global__ __launch_bounds__(256)
void gemm_f16(const _Float16* __restrict__ A, int lda,
              const _Float16* __restrict__ B,
              const float* __restrict__ bias,
              const float* __restrict__ pb0, const float* __restrict__ pb1,
              _Float16* __restrict__ lgt, float* __restrict__ aux,
              float2* __restrict__ partials, _Float16* __restrict__ h,
              int K, int Nvalid, int colOffset, int nTiles)
{
    __shared__ _Float16 As[128 * 64];
    __shared__ _Float16 Bs[128 * 64];

    const int t    = threadIdx.x;
    const int lane = t & 63;
    const int w    = t >> 6;
    const int wr   = w >> 1, wc = w & 1;
    const int q    = lane >> 4, cl = lane & 15;
    const int row0blk = blockIdx.y * 128;
    const int col0blk = blockIdx.x * 128;

    f32x4 acc[4][4];
#pragma unroll
    for (int m = 0; m < 4; ++m)
#pragma unroll
        for (int n = 0; n < 4; ++n)
            acc[m][n] = (f32x4){0.f, 0.f, 0.f, 0.f};

    for (int k0 = 0; k0 < K; k0 += 64) {
        __syncthreads();
#pragma unroll
        for (int iss = 0; iss < 4; ++iss) {
            int ci  = iss * 256 + w * 64 + lane;
            int row = ci >> 3;
            int ch  = (ci & 7) ^ (row & 7);     // inverse swizzle on source
            gload_lds16(A + (size_t)(row0blk + row) * lda + k0 + ch * 8,
                        As + (size_t)(iss * 256 + w * 64) * 8);
            gload_lds16(B + (size_t)(col0blk + row) * K + k0 + ch * 8,
                        Bs + (size_t)(iss * 256 + w * 64) * 8);
        }
        __syncthreads();

#pragma unroll
        for (int kk = 0; kk < 2; ++kk) {
            f16x8 a[4], b[4];
#pragma unroll
            for (int m = 0; m < 4; ++m) {
                int row = wr * 64 + m * 16 + cl;
                int ch  = (kk * 4 + q) ^ (row & 7);   // swizzled read
                a[m] = *(const f16x8*)(As + row * 64 + ch * 8);
            }
#pragma unroll
            for (int n = 0; n < 4; ++n) {
                int row = wc * 64 + n * 16 + cl;
                int ch  = (kk * 4 + q) ^ (row & 7);
                b[n] = *(const f16x8*)(Bs + row * 64 + ch * 8);
            }
#pragma unroll
            for (int m = 0; m < 4; ++m)
#pragma unroll
                for (int n = 0; n < 4; ++n)
                    acc[m][n] = __builtin_amdgcn_mfma_f32_16x16x32_f16(
                        a[m], b[n], acc[m][n], 0, 0, 0);
        }
    }
    __syncthreads();   // LDS reads done; safe to reuse As for reductions

    if (MODE == 3) {
#pragma unroll
        for (int m = 0; m < 4; ++m)
#pragma unroll
            for (int n = 0; n < 4; ++n) {
                int colseg = col0blk + wc * 64 + n * 16 + cl;
                if (colseg < PROJ_LD) {
                    float bv = (colseg < 256) ? pb0[colseg] : pb1[colseg - 256];
#pragma unroll
                    for (int j = 0; j < 4; ++j) {
                        int rg = row0blk + wr * 64 + m * 16 + q * 4 + j;
                        h[(size_t)rg * PROJ_LD + colseg] =
                            (_Float16)(acc[m][n][j] + bv);
                    }
                }
            }
        return;
    }

    // logits epilogue: f16 store + per-row partial (max, sumexp)
    float bn4[4];
#pragma unroll
    for (int n = 0; n < 4; ++n) {
        int colseg = col0blk + wc * 64 + n * 16 + cl;
        bn4[n] = (MODE == 1 && colseg < Nvalid) ? bias[colseg] : 0.f;
    }

    float* sred = (float*)As;   // [smax: 2x128][ssum: 2x128]

#pragma unroll
    for (int m = 0; m < 4; ++m)
#pragma unroll
        for (int j = 0; j < 4; ++j) {
            int rloc = wr * 64 + m * 16 + q * 4 + j;
            int rg   = row0blk + rloc;
            float vv[4];
            float mx = -1e30f;
#pragma unroll
            for (int n = 0; n < 4; ++n) {
                int colseg = col0blk + wc * 64 + n * 16 + cl;
                float v = acc[m][n][j] + bn4[n];
                bool ok = colseg < Nvalid;
                if (ok) {
                    if (MODE == 0 && colseg >= CUT0)
                        aux[rg * 2 + (colseg - CUT0)] = v;
                    else
                        lgt[(size_t)rg * VOCAB + colOffset + colseg] =
                            (_Float16)v;
                }
                vv[n] = ok ? v : -1e30f;
                mx = fmaxf(mx, vv[n]);
            }
            float sm = 0.f;
#pragma unroll
            for (int n = 0; n < 4; ++n) sm += __expf(vv[n] - mx);
#pragma unroll
            for (int d = 1; d < 16; d <<= 1) {
                float om = __shfl_xor(mx, d);
                float os = __shfl_xor(sm, d);
                float nm = fmaxf(mx, om);
                sm = sm * __expf(mx - nm) + os * __expf(om - nm);
                mx = nm;
            }
            if (cl == 0) {
                sred[wc * 128 + rloc]       = mx;
                sred[256 + wc * 128 + rloc] = sm;
            }
        }
    __syncthreads();
    if (t < 128) {
        float m1 = sred[t],       m2 = sred[128 + t];
        float s1 = sred[256 + t], s2 = sred[384 + t];
        float mm = fmaxf(m1, m2);
        float ss = s1 * __expf(m1 - mm) + s2 * __expf(m2 - mm);
        partials[(size_t)(row0blk + t) * nTiles + blockIdx.x] =
            make_float2(mm, ss);
    }
}

// ---------------------------------------------------------------------------
// reduce partials -> stats[r] = {C_root, C_seg1, C_seg2, 0}; p = exp(l - C)
// ---------------------------------------------------------------------------
__global__ __launch_bounds__(256)
void reduce_stats(const float2* __restrict__ P0, const float2* __restrict__ P1,
                  const float2* __restrict__ P2, const float* __restrict__ root2,
                  float* __restrict__ stats)
{
    __shared__ float sm[256], ss[256];
    const int r = blockIdx.x, t = threadIdx.x;
    const float2* Ps[3] = {P0, P1, P2};
    const int cnt[3] = {16, 63, 315};
    float M[3], L[3];

    for (int sg = 0; sg < 3; ++sg) {
        float m = -1e30f, s = 0.f;
        for (int i = t; i < cnt[sg]; i += 256) {
            float2 p = Ps[sg][(size_t)r * cnt[sg] + i];
            float mm = fmaxf(m, p.x);
            s = s * __expf(m - mm) + p.y * __expf(p.x - mm);
            m = mm;
        }
        sm[t] = m; ss[t] = s;
        __syncthreads();
        for (int w2 = 128; w2 > 0; w2 >>= 1) {
            if (t < w2) {
                float m1 = sm[t], m2 = sm[t + w2];
                float s1 = ss[t], s2 = ss[t + w2];
                float mm = fmaxf(m1, m2);
                sm[t] = mm;
                ss[t] = s1 * __expf(m1 - mm) + s2 * __expf(m2 - mm);
            }
            __syncthreads();
        }
        M[sg] = sm[0]; L[sg] = logf(ss[0]);
        __syncthreads();
    }

    if (t == 0) {
        float rm = M[0], rl = L[0];
        float clp0 = root2[r * 2 + 0] - rm - rl;
        float clp1 = root2[r * 2 + 1] - rm - rl;
        float4 st;
        st.x = rm + rl;            // root
        st.y = M[1] + L[1] - clp0; // cluster 0
        st.z = M[2] + L[2] - clp1; // cluster 1
        st.w = 0.f;
        ((float4*)stats)[r] = st;
    }
}

// ---------------------------------------------------------------------------
// finalize: out = exp(lgt_f16 - C_seg). Grid-stride, 4 halfs in / float4 out.
// ---------------------------------------------------------------------------
#define FIN_BLOCKS 4096
__global__ __launch_bounds__(256)
void finalize(const _Float16* __restrict__ lgt, const float4* __restrict__ stats,
              float4* __restrict__ out)
{
    const uint32_t T4 = (uint32_t)((size_t)ROWS * VOCAB / 4);   // 25,731,584
    for (uint32_t i4 = blockIdx.x * 256 + threadIdx.x; i4 < T4;
         i4 += FIN_BLOCKS * 256) {
        uint32_t e0 = i4 * 4;
        uint2 raw = *(const uint2*)(lgt + e0);
        union { uint32_t u; _Float16 h[2]; } pa, pb;
        pa.u = raw.x; pb.u = raw.y;
        float lv[4] = {(float)pa.h[0], (float)pa.h[1],
                       (float)pb.h[0], (float)pb.h[1]};
        float r4[4];
#pragma unroll
        for (int j = 0; j < 4; ++j) {
            uint32_t e = e0 + j;
            uint32_t r = e / (uint32_t)VOCAB;
            uint32_t c = e - r * (uint32_t)VOCAB;
            float4 st = stats[r];
            float C = (c < CUT0) ? st.x : ((c < CUT1) ? st.y : st.z);
            r4[j] = __expf(lv[j] - C);
        }
        out[i4] = make_float4(r4[0], r4[1], r4[2], r4[3]);
    }
}

// ---------------------------------------------------------------------------
extern "C" void kernel_launch(void* const* d_in, const int* in_sizes, int n_in,
                              void* d_out, int out_size, void* d_ws, size_t ws_size,
                              hipStream_t stream)
{
    (void)in_sizes; (void)n_in; (void)out_size; (void)ws_size;

    const float* x    = (const float*)d_in[0];
    const float* head = (const float*)d_in[2];
    const float* pk0  = (const float*)d_in[3];
    const float* pb0  = (const float*)d_in[4];
    const float* sk0  = (const float*)d_in[5];
    const float* sb0  = (const float*)d_in[6];
    const float* pk1  = (const float*)d_in[7];
    const float* pb1  = (const float*)d_in[8];
    const float* sk1  = (const float*)d_in[9];
    const float* sb1  = (const float*)d_in[10];

    float* out = (float*)d_out;
    char*  ws  = (char*)d_ws;

    // ws layout (bytes)
    _Float16* lgt   = (_Float16*)(ws);                 // 2048x50257 f16
    _Float16* A     = (_Float16*)(ws + 205852672);     // 2048x1024
    _Float16* headT = (_Float16*)(ws + 210046976);     // 2048x1024
    _Float16* pkT   = (_Float16*)(ws + 214241280);     // 384x1024
    _Float16* sk0T  = (_Float16*)(ws + 215027712);     // 8064x256
    _Float16* sk1T  = (_Float16*)(ws + 219156480);     // 40320x64
    _Float16* h     = (_Float16*)(ws + 224317440);     // 2048x320
    float*    root2 = (float*)(ws + 225628160);        // 2048x2
    float2*   P0    = (float2*)(ws + 225644544);       // 2048x16
    float2*   P1    = (float2*)(ws + 225906688);       // 2048x63
    float2*   P2    = (float2*)(ws + 226938880);       // 2048x315
    float*    stats = (float*)(ws + 232099840);        // 2048x4

    const dim3 blk(256);

    convert_all<<<dim3(9016), blk, 0, stream>>>(x, head, pk0, pk1, sk0, sk1,
                                                A, headT, pkT, sk0T, sk1T);

    // proj: h[2048,320] = x @ [pk0|pk1] + [pb0|pb1]
    gemm_f16<3><<<dim3(3, 16), blk, 0, stream>>>(A, DIM, pkT, nullptr,
        pb0, pb1, nullptr, nullptr, nullptr, h, 1024, PROJ_LD, 0, 0);

    // root logits -> lgt[:, :2000] (+aux) + partials P0
    gemm_f16<0><<<dim3(16, 16), blk, 0, stream>>>(A, DIM, headT, nullptr,
        nullptr, nullptr, lgt, root2, P0, nullptr, 1024, 2002, 0, 16);
    // scale0 -> lgt[:, 2000:10000] + partials P1
    gemm_f16<1><<<dim3(63, 16), blk, 0, stream>>>(h, PROJ_LD, sk0T, sb0,
        nullptr, nullptr, lgt, nullptr, P1, nullptr, 256, 8000, CUT0, 63);
    // scale1 -> lgt[:, 10000:50257] + partials P2
    gemm_f16<1><<<dim3(315, 16), blk, 0, stream>>>(h + 256, PROJ_LD, sk1T, sb1,
        nullptr, nullptr, lgt, nullptr, P2, nullptr, 64, 40257, CUT1, 315);

    reduce_stats<<<dim3(ROWS), blk, 0, stream>>>(P0, P1, P2, root2, stats);
    finalize<<<dim3(FIN_BLOCKS), blk, 0, stream>>>(lgt, (const float4*)stats,
                                                   (float4*)out);
}

// Round 5
// 311.546 us; speedup vs baseline: 4.7875x; 1.3665x over previous
//
#include <hip/hip_runtime.h>
#include <cstdint>
#include <cstddef>

#define ROWS    2048
#define DIM     1024
#define VOCAB   50257
#define CUT0    2000
#define CUT1    10000
#define PROJ_LD 320      // h columns: 256 (cluster0) + 64 (cluster1)
#define LGTC_LD 10016    // compact logit buffer row stride (10000 padded)

typedef __attribute__((ext_vector_type(8))) _Float16 f16x8;
typedef __attribute__((ext_vector_type(4))) float    f32x4;

__device__ __forceinline__ void gload_lds16(const void* g, void* l) {
    __builtin_amdgcn_global_load_lds(
        (const __attribute__((address_space(1))) void*)g,
        (__attribute__((address_space(3))) void*)l, 16, 0, 0);
}

// ---------------------------------------------------------------------------
// Kernel 1: conversions + zero the stats accumulators.
//   [0,2048)     : x f32 -> A f16 flat cast (2048x1024)
//   [2048,4096)  : head  [1024,2002] -> headT [2048,1024] (pad rows zeroed)
//   [4096,4352)  : pk0   [1024,256]  -> pkT rows [0,256)
//   [4352,4480)  : pk1   [1024,64]   -> pkT rows [256,384) (pad zero)
//   [4480,6496)  : sk0   [256,8000]  -> sk0T [8064,256]
//   [6496,9016)  : sk1   [64,40257]  -> sk1T [40320,64]
//   [9016,9024)  : zero S[2048][4]
// ---------------------------------------------------------------------------
__global__ __launch_bounds__(256)
void convert_all(const float* __restrict__ x, const float* __restrict__ head,
                 const float* __restrict__ pk0, const float* __restrict__ pk1,
                 const float* __restrict__ sk0, const float* __restrict__ sk1,
                 _Float16* __restrict__ A, _Float16* __restrict__ headT,
                 _Float16* __restrict__ pkT, _Float16* __restrict__ sk0T,
                 _Float16* __restrict__ sk1T, float* __restrict__ S)
{
    __shared__ float tile[32][33];
    const int bid = blockIdx.x, t = threadIdx.x;

    if (bid >= 9016) {                      // zero stats
        int i = (bid - 9016) * 256 + t;     // 2048 float4s
        ((float4*)S)[i] = make_float4(0.f, 0.f, 0.f, 0.f);
        return;
    }

    if (bid < 2048) {                       // flat cast of x
        int fid = bid * 256 + t;            // float4 index
        float4 v = ((const float4*)x)[fid];
        union { _Float16 h[4]; ushort4 u; } cv;
        cv.h[0] = (_Float16)v.x; cv.h[1] = (_Float16)v.y;
        cv.h[2] = (_Float16)v.z; cv.h[3] = (_Float16)v.w;
        ((ushort4*)A)[fid] = cv.u;
        return;
    }

    const float* src; _Float16* dst; int K, N, local, ntiles;
    if (bid < 4096)      { src = head; dst = headT;          K = 1024; N = 2002;  local = bid - 2048; ntiles = 64;  }
    else if (bid < 4352) { src = pk0;  dst = pkT;            K = 1024; N = 256;   local = bid - 4096; ntiles = 8;   }
    else if (bid < 4480) { src = pk1;  dst = pkT + 256*1024; K = 1024; N = 64;    local = bid - 4352; ntiles = 4;   }
    else if (bid < 6496) { src = sk0;  dst = sk0T;           K = 256;  N = 8000;  local = bid - 4480; ntiles = 252; }
    else                 { src = sk1;  dst = sk1T;           K = 64;   N = 40257; local = bid - 6496; ntiles = 1260;}

    const int bn = local % ntiles, bk = local / ntiles;
    const int tx = t & 31, ty = t >> 5;
    const int n0 = bn * 32, k0 = bk * 32;
#pragma unroll
    for (int i = 0; i < 4; ++i) {
        int kk = ty + i * 8;
        int n  = n0 + tx;
        tile[kk][tx] = (n < N) ? src[(size_t)(k0 + kk) * N + n] : 0.f;
    }
    __syncthreads();
#pragma unroll
    for (int i = 0; i < 4; ++i) {
        int nn = ty + i * 8;
        int r  = n0 + nn;
        dst[(size_t)r * K + k0 + tx] = (_Float16)tile[tx][nn];
    }
}

// ---------------------------------------------------------------------------
// Shared fp16 MFMA GEMM body, NT: C[M,N] = A[M,K](lda) . B[Npad,K]^T
// 128x128 tile, BK=64, 256 threads (4 waves 2x2), mfma_f32_16x16x32_f16.
// global_load_lds, XOR-swizzled source + swizzled ds_read (rule #21).
// MODE 0: root   -> lgtC[:, 0:2000) f16 + root2 + atomic S[r][0]
// MODE 1: scale0 -> lgtC[:, 2000:10000) f16 + bias + atomic S[r][1]
// MODE 2: scale1 pass1 -> bias + atomic S[r][2] only (no stores)
// MODE 3: proj   -> h[2048,320] f16 + split bias (pb0|pb1)
// MODE 4: scale1 pass2 -> out[:, 10000+c] = exp(l)*scale directly (f32)
// ---------------------------------------------------------------------------
template<int MODE>
__device__ __forceinline__ void gemm_body(
    _Float16* As, _Float16* Bs,
    const _Float16* __restrict__ A, int lda,
    const _Float16* __restrict__ B, int K,
    int bx, int by, int Nvalid,
    const float* __restrict__ bias,
    const float* __restrict__ pb0, const float* __restrict__ pb1,
    _Float16* __restrict__ lgtC, float* __restrict__ root2,
    float* __restrict__ S, float* __restrict__ outF,
    _Float16* __restrict__ h)
{
    const int t    = threadIdx.x;
    const int lane = t & 63;
    const int w    = t >> 6;
    const int wr   = w >> 1, wc = w & 1;
    const int q    = lane >> 4, cl = lane & 15;
    const int row0blk = by * 128;
    const int col0blk = bx * 128;

    f32x4 acc[4][4];
#pragma unroll
    for (int m = 0; m < 4; ++m)
#pragma unroll
        for (int n = 0; n < 4; ++n)
            acc[m][n] = (f32x4){0.f, 0.f, 0.f, 0.f};

    for (int k0 = 0; k0 < K; k0 += 64) {
        __syncthreads();
#pragma unroll
        for (int iss = 0; iss < 4; ++iss) {
            int ci  = iss * 256 + w * 64 + lane;
            int row = ci >> 3;
            int ch  = (ci & 7) ^ (row & 7);     // inverse swizzle on source
            gload_lds16(A + (size_t)(row0blk + row) * lda + k0 + ch * 8,
                        As + (size_t)(iss * 256 + w * 64) * 8);
            gload_lds16(B + (size_t)(col0blk + row) * K + k0 + ch * 8,
                        Bs + (size_t)(iss * 256 + w * 64) * 8);
        }
        __syncthreads();

#pragma unroll
        for (int kk = 0; kk < 2; ++kk) {
            f16x8 a[4], b[4];
#pragma unroll
            for (int m = 0; m < 4; ++m) {
                int row = wr * 64 + m * 16 + cl;
                int ch  = (kk * 4 + q) ^ (row & 7);   // swizzled read
                a[m] = *(const f16x8*)(As + row * 64 + ch * 8);
            }
#pragma unroll
            for (int n = 0; n < 4; ++n) {
                int row = wc * 64 + n * 16 + cl;
                int ch  = (kk * 4 + q) ^ (row & 7);
                b[n] = *(const f16x8*)(Bs + row * 64 + ch * 8);
            }
#pragma unroll
            for (int m = 0; m < 4; ++m)
#pragma unroll
                for (int n = 0; n < 4; ++n)
                    acc[m][n] = __builtin_amdgcn_mfma_f32_16x16x32_f16(
                        a[m], b[n], acc[m][n], 0, 0, 0);
        }
    }
    __syncthreads();   // LDS reads done; As reusable for reductions

    if (MODE == 3) {   // proj epilogue
#pragma unroll
        for (int m = 0; m < 4; ++m)
#pragma unroll
            for (int n = 0; n < 4; ++n) {
                int colseg = col0blk + wc * 64 + n * 16 + cl;
                if (colseg < PROJ_LD) {
                    float bv = (colseg < 256) ? pb0[colseg] : pb1[colseg - 256];
#pragma unroll
                    for (int j = 0; j < 4; ++j) {
                        int rg = row0blk + wr * 64 + m * 16 + q * 4 + j;
                        h[(size_t)rg * PROJ_LD + colseg] =
                            (_Float16)(acc[m][n][j] + bv);
                    }
                }
            }
        return;
    }

    // bias per column (hoisted)
    float bn4[4];
#pragma unroll
    for (int n = 0; n < 4; ++n) {
        int colseg = col0blk + wc * 64 + n * 16 + cl;
        bn4[n] = (MODE != 0 && colseg < Nvalid) ? bias[colseg] : 0.f;
    }

    if (MODE == 4) {   // scale1 pass2: direct probability write
#pragma unroll
        for (int m = 0; m < 4; ++m)
#pragma unroll
            for (int j = 0; j < 4; ++j) {
                int rg = row0blk + wr * 64 + m * 16 + q * 4 + j;
                float4 S4 = ((const float4*)S)[rg];
                float scl = __expf(root2[rg * 2 + 1]) / (S4.z * S4.x);
                size_t rb = (size_t)rg * VOCAB + CUT1;
#pragma unroll
                for (int n = 0; n < 4; ++n) {
                    int c = col0blk + wc * 64 + n * 16 + cl;
                    if (c < Nvalid)
                        outF[rb + c] = __expf(acc[m][n][j] + bn4[n]) * scl;
                }
            }
        return;
    }

    // MODES 0/1/2: optional f16 logit store + Σexp accumulation
    float* sred = (float*)As;
#pragma unroll
    for (int m = 0; m < 4; ++m)
#pragma unroll
        for (int j = 0; j < 4; ++j) {
            int rloc = wr * 64 + m * 16 + q * 4 + j;
            int rg   = row0blk + rloc;
            float sm = 0.f;
#pragma unroll
            for (int n = 0; n < 4; ++n) {
                int c = col0blk + wc * 64 + n * 16 + cl;
                float v = acc[m][n][j] + bn4[n];
                bool ok = c < Nvalid;
                if (MODE == 0 && ok) {
                    if (c < CUT0)
                        lgtC[(size_t)rg * LGTC_LD + c] = (_Float16)v;
                    else
                        root2[rg * 2 + (c - CUT0)] = v;
                }
                if (MODE == 1 && ok)
                    lgtC[(size_t)rg * LGTC_LD + CUT0 + c] = (_Float16)v;
                sm += ok ? __expf(v) : 0.f;
            }
#pragma unroll
            for (int d = 1; d < 16; d <<= 1)
                sm += __shfl_xor(sm, d);
            if (cl == 0) sred[wc * 128 + rloc] = sm;
        }
    __syncthreads();
    if (t < 128) {
        const int sidx = (MODE == 0) ? 0 : (MODE == 1 ? 1 : 2);
        atomicAdd(&S[(row0blk + t) * 4 + sidx], sred[t] + sred[128 + t]);
    }
}

// ---------------------------------------------------------------------------
// Kernel 2: proj (48 WGs) + root (256 WGs)
// ---------------------------------------------------------------------------
__global__ __launch_bounds__(256)
void k2_projroot(const _Float16* __restrict__ A, const _Float16* __restrict__ pkT,
                 const _Float16* __restrict__ headT,
                 const float* __restrict__ pb0, const float* __restrict__ pb1,
                 _Float16* __restrict__ h, _Float16* __restrict__ lgtC,
                 float* __restrict__ root2, float* __restrict__ S)
{
    __shared__ _Float16 As[128 * 64];
    __shared__ _Float16 Bs[128 * 64];
    const int bid = blockIdx.x;
    if (bid < 48)
        gemm_body<3>(As, Bs, A, DIM, pkT, 1024, bid % 3, bid / 3, PROJ_LD,
                     nullptr, pb0, pb1, nullptr, nullptr, nullptr, nullptr, h);
    else {
        int i = bid - 48;
        gemm_body<0>(As, Bs, A, DIM, headT, 1024, i % 16, i / 16, 2002,
                     nullptr, nullptr, nullptr, lgtC, root2, S, nullptr, nullptr);
    }
}

// ---------------------------------------------------------------------------
// Kernel 3: scale0 (1008 WGs) + scale1 pass1 (5040 WGs)
// ---------------------------------------------------------------------------
__global__ __launch_bounds__(256)
void k3_scales(const _Float16* __restrict__ h, const _Float16* __restrict__ sk0T,
               const _Float16* __restrict__ sk1T,
               const float* __restrict__ sb0, const float* __restrict__ sb1,
               _Float16* __restrict__ lgtC, float* __restrict__ S)
{
    __shared__ _Float16 As[128 * 64];
    __shared__ _Float16 Bs[128 * 64];
    const int bid = blockIdx.x;
    if (bid < 1008)
        gemm_body<1>(As, Bs, h, PROJ_LD, sk0T, 256, bid % 63, bid / 63, 8000,
                     sb0, nullptr, nullptr, lgtC, nullptr, S, nullptr, nullptr);
    else {
        int i = bid - 1008;
        gemm_body<2>(As, Bs, h + 256, PROJ_LD, sk1T, 64, i % 315, i / 315, 40257,
                     sb1, nullptr, nullptr, nullptr, nullptr, S, nullptr, nullptr);
    }
}

// ---------------------------------------------------------------------------
// Kernel 4: scale1 pass2 (5040 WGs, direct out write) + finalize rows (2048 WGs)
// ---------------------------------------------------------------------------
__global__ __launch_bounds__(256)
void k4_megafin(const _Float16* __restrict__ h, const _Float16* __restrict__ sk1T,
                const float* __restrict__ sb1, const _Float16* __restrict__ lgtC,
                const float* __restrict__ root2, const float* __restrict__ S,
                float* __restrict__ outF)
{
    __shared__ _Float16 As[128 * 64];
    __shared__ _Float16 Bs[128 * 64];
    const int bid = blockIdx.x;
    if (bid < 5040) {
        gemm_body<4>(As, Bs, h + 256, PROJ_LD, sk1T, 64, bid % 315, bid / 315,
                     40257, sb1, nullptr, nullptr, nullptr,
                     (float*)root2, (float*)S, outF, nullptr);
        return;
    }
    // finalize cols [0,10000) for row r from compact f16 logits
    const int r = bid - 5040;
    float4 S4 = ((const float4*)S)[r];
    float inv_r = 1.f / S4.x;
    float sc0   = __expf(root2[r * 2 + 0]) / (S4.y * S4.x);
    const _Float16* lrow = lgtC + (size_t)r * LGTC_LD;
    float* orow = outF + (size_t)r * VOCAB;
    for (int i4 = threadIdx.x; i4 < LGTC_LD / 4; i4 += 256) {
        uint2 raw = *(const uint2*)(lrow + i4 * 4);
        union { uint32_t u; _Float16 hh[2]; } pa, pb;
        pa.u = raw.x; pb.u = raw.y;
        float lv[4] = {(float)pa.hh[0], (float)pa.hh[1],
                       (float)pb.hh[0], (float)pb.hh[1]};
        int c0 = i4 * 4;
#pragma unroll
        for (int j = 0; j < 4; ++j) {
            int c = c0 + j;
            if (c < CUT1) {
                float sc = (c < CUT0) ? inv_r : sc0;
                orow[c] = __expf(lv[j]) * sc;
            }
        }
    }
}

// ---------------------------------------------------------------------------
extern "C" void kernel_launch(void* const* d_in, const int* in_sizes, int n_in,
                              void* d_out, int out_size, void* d_ws, size_t ws_size,
                              hipStream_t stream)
{
    (void)in_sizes; (void)n_in; (void)out_size; (void)ws_size;

    const float* x    = (const float*)d_in[0];
    const float* head = (const float*)d_in[2];
    const float* pk0  = (const float*)d_in[3];
    const float* pb0  = (const float*)d_in[4];
    const float* sk0  = (const float*)d_in[5];
    const float* sb0  = (const float*)d_in[6];
    const float* pk1  = (const float*)d_in[7];
    const float* pb1  = (const float*)d_in[8];
    const float* sk1  = (const float*)d_in[9];
    const float* sb1  = (const float*)d_in[10];

    float* out = (float*)d_out;
    char*  ws  = (char*)d_ws;

    // ws layout (bytes, all 256-aligned)
    _Float16* lgtC  = (_Float16*)(ws);                 // 2048x10016 f16
    _Float16* A     = (_Float16*)(ws + 41025536);      // 2048x1024
    _Float16* headT = (_Float16*)(ws + 45219840);      // 2048x1024
    _Float16* pkT   = (_Float16*)(ws + 49414144);      // 384x1024
    _Float16* sk0T  = (_Float16*)(ws + 50200576);      // 8064x256
    _Float16* sk1T  = (_Float16*)(ws + 54329344);      // 40320x64
    _Float16* h     = (_Float16*)(ws + 59490304);      // 2048x320
    float*    root2 = (float*)(ws + 60801024);         // 2048x2
    float*    S     = (float*)(ws + 60817408);         // 2048x4 {Sr,S0,S1,-}

    const dim3 blk(256);

    convert_all<<<dim3(9024), blk, 0, stream>>>(x, head, pk0, pk1, sk0, sk1,
                                                A, headT, pkT, sk0T, sk1T, S);
    k2_projroot<<<dim3(304), blk, 0, stream>>>(A, pkT, headT, pb0, pb1,
                                               h, lgtC, root2, S);
    k3_scales<<<dim3(6048), blk, 0, stream>>>(h, sk0T, sk1T, sb0, sb1, lgtC, S);
    k4_megafin<<<dim3(7088), blk, 0, stream>>>(h, sk1T, sb1, lgtC, root2, S, out);
}